// Round 1
// baseline (175.374 us; speedup 1.0000x reference)
//
#include <hip/hip_runtime.h>
#include <hip/hip_bf16.h>

typedef __attribute__((ext_vector_type(8))) short bf16x8;
typedef __attribute__((ext_vector_type(4))) short bf16x4;
typedef __attribute__((ext_vector_type(4))) float f32x4;

#define SCALE 0.08838834764831845f
#define NSEQ 2048
#define DH 128
#define QBLK 64
#define KVB 64

// RNE f32 -> bf16 (inputs finite, no NaN handling needed)
__device__ __forceinline__ short f2bf(float x) {
  unsigned int u = __float_as_uint(x);
  unsigned int r = (u + 0x7fffu + ((u >> 16) & 1u)) >> 16;
  return (short)r;
}

// LDS swizzle for the transposed V tile rows (d = row, 128B rows)
__device__ __forceinline__ int swzT(int d) {
  return ((d & 7) ^ ((d >> 3) & 7)) << 4;
}

__global__ __launch_bounds__(256, 2) void attn_fwd(
    const float* __restrict__ x1, const float* __restrict__ x2,
    float* __restrict__ out) {
  __shared__ char lds[40960];
  char* kvA = lds;            // [64 keys][128 d] bf16, 256B rows, swz=(key&7)<<4
  char* kvT = lds + 16384;    // [128 d][64 keys] bf16, 128B rows, swz=swzT(d)
  char* plds = lds + 32768;   // 4 waves x [16 q][64 k] bf16, 128B rows, swz=(q&7)<<4

  const int tid = threadIdx.x;
  const int lane = tid & 63;
  const int wid = tid >> 6;
  const int g = lane >> 4;    // 0..3
  const int q15 = lane & 15;  // q-row within wave tile / mfma col

  const int bb = blockIdx.y;
  const int qbase = blockIdx.x * QBLK + wid * 16;

  const float* x1b = x1 + (size_t)bb * NSEQ * DH;
  const float* x2b = x2 + (size_t)bb * NSEQ * DH;

  // Q fragments in B-layout for swapped QK^T: lane holds Q[qbase+q15][c*32+g*8+i]
  bf16x8 qf[4];
  {
    const float* qp = x1b + (size_t)(qbase + q15) * DH + g * 8;
#pragma unroll
    for (int c = 0; c < 4; ++c) {
      f32x4 v0 = *(const f32x4*)(qp + c * 32);
      f32x4 v1 = *(const f32x4*)(qp + c * 32 + 4);
      bf16x8 f;
#pragma unroll
      for (int i = 0; i < 4; ++i) { f[i] = f2bf(v0[i]); f[i + 4] = f2bf(v1[i]); }
      qf[c] = f;
    }
  }

  float m_run = -1e30f;
  float l_run = 0.f;
  f32x4 o[8];
#pragma unroll
  for (int dc = 0; dc < 8; ++dc) o[dc] = (f32x4){0.f, 0.f, 0.f, 0.f};

  for (int kv0 = 0; kv0 < NSEQ; kv0 += KVB) {
    __syncthreads();  // protect previous-iter LDS reads from new staging
    // ---- stage KV tile (64 keys x 128 d), both layouts, f32 -> bf16 ----
#pragma unroll
    for (int p = 0; p < 4; ++p) {
      const int key = p * 16 + (tid >> 4);
      const int dg = tid & 15;
      const float* src = x2b + (size_t)(kv0 + key) * DH + dg * 8;
      f32x4 v0 = *(const f32x4*)src;
      f32x4 v1 = *(const f32x4*)(src + 4);
      short s8[8];
#pragma unroll
      for (int i = 0; i < 4; ++i) { s8[i] = f2bf(v0[i]); s8[i + 4] = f2bf(v1[i]); }
      bf16x8 pack;
#pragma unroll
      for (int i = 0; i < 8; ++i) pack[i] = s8[i];
      *(bf16x8*)(kvA + key * 256 + ((dg * 16) ^ ((key & 7) << 4))) = pack;
#pragma unroll
      for (int i = 0; i < 8; ++i) {
        const int d = dg * 8 + i;
        *(short*)(kvT + d * 128 + ((key * 2) ^ swzT(d))) = s8[i];
      }
    }
    __syncthreads();

    // ---- swapped QK^T: sf[kb] = K(16 keys x D) . Q^T  -> D[key_local][q] ----
    f32x4 sf[4];
#pragma unroll
    for (int kb = 0; kb < 4; ++kb) {
      sf[kb] = (f32x4){0.f, 0.f, 0.f, 0.f};
      const int key = kb * 16 + q15;  // A-frag row = lane&15
#pragma unroll
      for (int c = 0; c < 4; ++c) {
        bf16x8 a = *(const bf16x8*)(kvA + key * 256 +
                                    ((c * 64 + g * 16) ^ ((key & 7) << 4)));
        sf[kb] = __builtin_amdgcn_mfma_f32_16x16x32_bf16(a, qf[c], sf[kb], 0, 0, 0);
      }
    }

    // ---- online softmax for q = qbase + q15 (keys kb*16 + g*4 + r per lane) ----
    float mloc = -1e30f;
#pragma unroll
    for (int kb = 0; kb < 4; ++kb)
#pragma unroll
      for (int r = 0; r < 4; ++r) mloc = fmaxf(mloc, sf[kb][r]);
    mloc = fmaxf(mloc, __shfl_xor(mloc, 16));
    mloc = fmaxf(mloc, __shfl_xor(mloc, 32));
    mloc *= SCALE;
    const float mnew = fmaxf(m_run, mloc);
    const float corr = __expf(m_run - mnew);
    float tsum = 0.f;
    short pb[4][4];
#pragma unroll
    for (int kb = 0; kb < 4; ++kb)
#pragma unroll
      for (int r = 0; r < 4; ++r) {
        float pv = __expf(sf[kb][r] * SCALE - mnew);
        tsum += pv;
        pb[kb][r] = f2bf(pv);
      }
    tsum += __shfl_xor(tsum, 16);
    tsum += __shfl_xor(tsum, 32);
    l_run = l_run * corr + tsum;
    m_run = mnew;

    // ---- rescale O accumulators (row q' = g*4 + r; factor lives at lane q') ----
#pragma unroll
    for (int r = 0; r < 4; ++r) {
      const float fr = __shfl(corr, g * 4 + r);
#pragma unroll
      for (int dc = 0; dc < 8; ++dc) o[dc][r] *= fr;
    }

    // ---- P -> per-wave LDS (convert S^T D-layout to PV A-layout) ----
#pragma unroll
    for (int kb = 0; kb < 4; ++kb) {
      bf16x4 pk;
#pragma unroll
      for (int r = 0; r < 4; ++r) pk[r] = pb[kb][r];
      *(bf16x4*)(plds + wid * 2048 + q15 * 128 +
                 ((kb * 32 + g * 8) ^ ((q15 & 7) << 4))) = pk;
    }

    // ---- PV: O[q][d] += P(16x64) . V(64x128) ----
#pragma unroll
    for (int kc = 0; kc < 2; ++kc) {
      bf16x8 pa = *(const bf16x8*)(plds + wid * 2048 + q15 * 128 +
                                   ((kc * 64 + g * 16) ^ ((q15 & 7) << 4)));
#pragma unroll
      for (int dc = 0; dc < 8; ++dc) {
        const int d = dc * 16 + q15;  // B-frag col = lane&15
        bf16x8 vb = *(const bf16x8*)(kvT + d * 128 +
                                     ((kc * 64 + g * 16) ^ swzT(d)));
        o[dc] = __builtin_amdgcn_mfma_f32_16x16x32_bf16(pa, vb, o[dc], 0, 0, 0);
      }
    }
  }

  // ---- epilogue: normalize by l and store fp32 ----
#pragma unroll
  for (int r = 0; r < 4; ++r) {
    const float linv = 1.0f / __shfl(l_run, g * 4 + r);
    const int q = qbase + g * 4 + r;
    float* op = out + (size_t)bb * NSEQ * DH + (size_t)q * DH + q15;
#pragma unroll
    for (int dc = 0; dc < 8; ++dc) op[dc * 16] = o[dc][r] * linv;
  }
}

extern "C" void kernel_launch(void* const* d_in, const int* in_sizes, int n_in,
                              void* d_out, int out_size, void* d_ws, size_t ws_size,
                              hipStream_t stream) {
  const float* x1 = (const float*)d_in[0];
  const float* x2 = (const float*)d_in[1];
  float* out = (float*)d_out;
  dim3 grid(NSEQ / QBLK, 16);
  attn_fwd<<<grid, dim3(256), 0, stream>>>(x1, x2, out);
}

// Round 3
// 148.189 us; speedup vs baseline: 1.1835x; 1.1835x over previous
//
#include <hip/hip_runtime.h>
#include <hip/hip_bf16.h>

typedef __attribute__((ext_vector_type(8))) short bf16x8;
typedef __attribute__((ext_vector_type(4))) short bf16x4;
typedef __attribute__((ext_vector_type(4))) float f32x4;

#define NSEQ 2048
#define DH 128
#define QBLK 64
#define KVB 64

// Fold softmax scale (and log2e when exp2 is available) into the Q conversion.
#if __has_builtin(__builtin_amdgcn_exp2f)
#define FEXP(x) __builtin_amdgcn_exp2f(x)
#define QSCALE 0.12751743f /* (1/sqrt(128)) * log2(e) */
#else
#define FEXP(x) __expf(x)
#define QSCALE 0.08838834764831845f
#endif

// RNE f32 -> bf16 (inputs finite, no NaN handling needed)
__device__ __forceinline__ short f2bf(float x) {
  unsigned int u = __float_as_uint(x);
  unsigned int r = (u + 0x7fffu + ((u >> 16) & 1u)) >> 16;
  return (short)r;
}

// LDS swizzle for the transposed V tile rows (d = row, 128B rows)
__device__ __forceinline__ int swzT(int d) {
  return ((d & 7) ^ ((d >> 3) & 7)) << 4;
}

__global__ __launch_bounds__(256, 2) void attn_fwd(
    const float* __restrict__ x1, const float* __restrict__ x2,
    float* __restrict__ out) {
  __shared__ char lds[40960];
  char* kvA = lds;            // [64 keys][128 d] bf16, 256B rows, swz=(key&7)<<4
  char* kvT = lds + 16384;    // [128 d][64 keys] bf16, 128B rows, swz=swzT(d)
  char* plds = lds + 32768;   // 4 waves x [16 q][64 k] bf16, swz=(q&7)<<4

  const int tid = threadIdx.x;
  const int lane = tid & 63;
  const int wid = tid >> 6;
  const int g = lane >> 4;    // 0..3
  const int q15 = lane & 15;  // q-row within wave tile / mfma col

  const int bb = blockIdx.y;
  const int qbase = blockIdx.x * QBLK + wid * 16;

  const float* x1b = x1 + (size_t)bb * NSEQ * DH;
  const float* x2b = x2 + (size_t)bb * NSEQ * DH;

  // Q fragments (B-layout for swapped QK^T), pre-scaled by QSCALE
  bf16x8 qf[4];
  {
    const float* qp = x1b + (size_t)(qbase + q15) * DH + g * 8;
#pragma unroll
    for (int c = 0; c < 4; ++c) {
      f32x4 v0 = *(const f32x4*)(qp + c * 32);
      f32x4 v1 = *(const f32x4*)(qp + c * 32 + 4);
      bf16x8 f;
#pragma unroll
      for (int i = 0; i < 4; ++i) {
        f[i] = f2bf(v0[i] * QSCALE);
        f[i + 4] = f2bf(v1[i] * QSCALE);
      }
      qf[c] = f;
    }
  }

  // ---- staging identity: thread owns keys kgrp*4..+3, d = dg*8..+7 ----
  const int kgrp = tid >> 4;  // 0..15
  const int dg = tid & 15;    // 0..15
  f32x4 ra[4][2];             // prefetch regs: [p = key sub][half of 8 d]

  auto LOADRA = [&](int kv0) {
    if (kv0 < NSEQ) {
#pragma unroll
      for (int p = 0; p < 4; ++p) {
        const float* s = x2b + (size_t)(kv0 + kgrp * 4 + p) * DH + dg * 8;
        ra[p][0] = *(const f32x4*)s;
        ra[p][1] = *(const f32x4*)(s + 4);
      }
    }
  };

  auto WRITELDS = [&]() {
    short sb[4][8];
#pragma unroll
    for (int p = 0; p < 4; ++p)
#pragma unroll
      for (int j = 0; j < 8; ++j) sb[p][j] = f2bf(ra[p][j >> 2][j & 3]);
    // kvA: row-major, one bf16x8 per key
#pragma unroll
    for (int p = 0; p < 4; ++p) {
      const int key = kgrp * 4 + p;
      bf16x8 pack;
#pragma unroll
      for (int j = 0; j < 8; ++j) pack[j] = sb[p][j];
      *(bf16x8*)(kvA + key * 256 + ((dg * 16) ^ ((key & 7) << 4))) = pack;
    }
    // kvT: transposed, 4-key column chunks as b64 stores (2-way banks = free)
#pragma unroll
    for (int i = 0; i < 8; ++i) {
      const int d = dg * 8 + i;
      bf16x4 col;
#pragma unroll
      for (int p = 0; p < 4; ++p) col[p] = sb[p][i];
      *(bf16x4*)(kvT + d * 128 + ((kgrp * 8) ^ swzT(d))) = col;
    }
  };

  float m_run = -1e30f;
  float l_run = 0.f;
  f32x4 o[8];
#pragma unroll
  for (int dc = 0; dc < 8; ++dc) o[dc] = (f32x4){0.f, 0.f, 0.f, 0.f};

  // ---- prologue: tile0 -> LDS, prefetch tile1 ----
  LOADRA(0);
  WRITELDS();
  LOADRA(KVB);
  asm volatile("s_waitcnt lgkmcnt(0)" ::: "memory");
  __builtin_amdgcn_s_barrier();

  for (int kv0 = 0; kv0 < NSEQ; kv0 += KVB) {
    // ---- swapped QK^T: sf[kb] = K(16 keys x D) . Q^T -> D[key_local][q] ----
    f32x4 sf[4];
#pragma unroll
    for (int kb = 0; kb < 4; ++kb) {
      sf[kb] = (f32x4){0.f, 0.f, 0.f, 0.f};
      const int key = kb * 16 + q15;  // A-frag row = lane&15
#pragma unroll
      for (int c = 0; c < 4; ++c) {
        bf16x8 a = *(const bf16x8*)(kvA + key * 256 +
                                    ((c * 64 + g * 16) ^ ((key & 7) << 4)));
        sf[kb] = __builtin_amdgcn_mfma_f32_16x16x32_bf16(a, qf[c], sf[kb], 0, 0, 0);
      }
    }

    // ---- online softmax (scores already scaled; exp2 domain) ----
    float mloc = -1e30f;
#pragma unroll
    for (int kb = 0; kb < 4; ++kb)
#pragma unroll
      for (int r = 0; r < 4; ++r) mloc = fmaxf(mloc, sf[kb][r]);
    mloc = fmaxf(mloc, __shfl_xor(mloc, 16));
    mloc = fmaxf(mloc, __shfl_xor(mloc, 32));
    const float mnew = fmaxf(m_run, mloc);
    const float corr = FEXP(m_run - mnew);
    float tsum = 0.f;
    short pb[4][4];
#pragma unroll
    for (int kb = 0; kb < 4; ++kb)
#pragma unroll
      for (int r = 0; r < 4; ++r) {
        float pv = FEXP(sf[kb][r] - mnew);
        tsum += pv;
        pb[kb][r] = f2bf(pv);
      }
    tsum += __shfl_xor(tsum, 16);
    tsum += __shfl_xor(tsum, 32);
    l_run = l_run * corr + tsum;
    m_run = mnew;

    // ---- rescale O (row q' = g*4 + r; factor lives at lane q') ----
#pragma unroll
    for (int r = 0; r < 4; ++r) {
      const float fr = __shfl(corr, g * 4 + r);
#pragma unroll
      for (int dc = 0; dc < 8; ++dc) o[dc][r] *= fr;
    }

    // ---- P -> per-wave LDS (S^T D-layout -> PV A-layout) ----
#pragma unroll
    for (int kb = 0; kb < 4; ++kb) {
      bf16x4 pk;
#pragma unroll
      for (int r = 0; r < 4; ++r) pk[r] = pb[kb][r];
      *(bf16x4*)(plds + wid * 2048 + q15 * 128 +
                 ((kb * 32 + g * 8) ^ ((q15 & 7) << 4))) = pk;
    }

    // ---- PV: O[q][d] += P(16x64) . V(64x128) ----
#pragma unroll
    for (int kc = 0; kc < 2; ++kc) {
      bf16x8 pa = *(const bf16x8*)(plds + wid * 2048 + q15 * 128 +
                                   ((kc * 64 + g * 16) ^ ((q15 & 7) << 4)));
#pragma unroll
      for (int dc = 0; dc < 8; ++dc) {
        const int d = dc * 16 + q15;  // B-frag col = lane&15
        bf16x8 vb = *(const bf16x8*)(kvT + d * 128 +
                                     ((kc * 64 + g * 16) ^ swzT(d)));
        o[dc] = __builtin_amdgcn_mfma_f32_16x16x32_bf16(pa, vb, o[dc], 0, 0, 0);
      }
    }

    // ---- rotate buffers: write prefetched tile, issue next prefetch ----
    if (kv0 + KVB < NSEQ) {
      __syncthreads();            // all waves done reading current LDS tile
      WRITELDS();                 // ra holds tile kv0+KVB
      LOADRA(kv0 + 2 * KVB);      // prefetch lands during next compute
      asm volatile("s_waitcnt lgkmcnt(0)" ::: "memory");
      __builtin_amdgcn_s_barrier();  // raw barrier: no vmcnt(0) drain
    }
  }

  // ---- epilogue: normalize by l and store fp32 ----
#pragma unroll
  for (int r = 0; r < 4; ++r) {
    const float linv = 1.0f / __shfl(l_run, g * 4 + r);
    const int q = qbase + g * 4 + r;
    float* op = out + (size_t)bb * NSEQ * DH + (size_t)q * DH + q15;
#pragma unroll
    for (int dc = 0; dc < 8; ++dc) op[dc * 16] = o[dc][r] * linv;
  }
}

extern "C" void kernel_launch(void* const* d_in, const int* in_sizes, int n_in,
                              void* d_out, int out_size, void* d_ws, size_t ws_size,
                              hipStream_t stream) {
  const float* x1 = (const float*)d_in[0];
  const float* x2 = (const float*)d_in[1];
  float* out = (float*)d_out;
  dim3 grid(NSEQ / QBLK, 16);
  attn_fwd<<<grid, dim3(256), 0, stream>>>(x1, x2, out);
}

// Round 5
// 134.439 us; speedup vs baseline: 1.3045x; 1.1023x over previous
//
#include <hip/hip_runtime.h>
#include <hip/hip_bf16.h>

typedef __attribute__((ext_vector_type(8))) short bf16x8;
typedef __attribute__((ext_vector_type(4))) float f32x4;
typedef __attribute__((ext_vector_type(4))) unsigned u32x4;
typedef __attribute__((ext_vector_type(2))) unsigned u32x2;

#define NSEQ 2048
#define DH 128
#define QBLK 64
#define KVB 64
#define QSCALE 0.12751744716167933f /* (1/sqrt(128)) * log2(e) */
#define DEFER_THR 8.0f
#define KVSTRIDE 32768  /* kvA 16KB + kvT 16KB per buffer */

__device__ __forceinline__ unsigned cvtpk(float lo, float hi) {
  unsigned r;
  asm("v_cvt_pk_bf16_f32 %0, %1, %2" : "=v"(r) : "v"(lo), "v"(hi));
  return r;
}
__device__ __forceinline__ float fexp2(float x) { return __builtin_amdgcn_exp2f(x); }

// LDS swizzle for the transposed V tile rows (d = row, 128B rows)
__device__ __forceinline__ int swzT(int d) {
  return ((d & 7) ^ ((d >> 3) & 7)) << 4;
}

__global__ __launch_bounds__(256, 2) void attn_fwd(
    const float* __restrict__ x1, const float* __restrict__ x2,
    float* __restrict__ out) {
  // Double-buffered KV: buf b at lds + b*32768 (kvA 16KB + kvT 16KB); plds at 64KB.
  __shared__ char lds[73728];
  char* plds = lds + 65536;  // 4 waves x 2KB, swz=(q&7)<<4

  const int tid = threadIdx.x;
  const int lane = tid & 63;
  const int wid = tid >> 6;
  const int g = lane >> 4;    // 0..3
  const int q15 = lane & 15;  // mfma col index

  const int bb = blockIdx.y;
  const int qbase = blockIdx.x * QBLK + wid * 16;

  const float* x1b = x1 + (size_t)bb * NSEQ * DH;
  const float* x2b = x2 + (size_t)bb * NSEQ * DH;

  // Q fragments (B-layout for swapped QK^T), pre-scaled by QSCALE, packed bf16
  u32x4 qf[4];
  {
    const float* qp = x1b + (size_t)(qbase + q15) * DH + g * 8;
#pragma unroll
    for (int c = 0; c < 4; ++c) {
      f32x4 v0 = *(const f32x4*)(qp + c * 32);
      f32x4 v1 = *(const f32x4*)(qp + c * 32 + 4);
      u32x4 w;
      w[0] = cvtpk(v0[0] * QSCALE, v0[1] * QSCALE);
      w[1] = cvtpk(v0[2] * QSCALE, v0[3] * QSCALE);
      w[2] = cvtpk(v1[0] * QSCALE, v1[1] * QSCALE);
      w[3] = cvtpk(v1[2] * QSCALE, v1[3] * QSCALE);
      qf[c] = w;
    }
  }

  // ---- staging identity: thread owns keys kgrp*4..+3, d = dg*8..+7 ----
  const int kgrp = tid >> 4;  // 0..15
  const int dg = tid & 15;    // 0..15
  f32x4 ra[4][2];             // prefetch regs

  auto LOADRA = [&](int kv0) {
    if (kv0 < NSEQ) {
#pragma unroll
      for (int p = 0; p < 4; ++p) {
        const float* s = x2b + (size_t)(kv0 + kgrp * 4 + p) * DH + dg * 8;
        ra[p][0] = *(const f32x4*)s;
        ra[p][1] = *(const f32x4*)(s + 4);
      }
    }
  };

  auto WRITELDS = [&](int b) {
    char* kvAb = lds + b * KVSTRIDE;
    char* kvTb = kvAb + 16384;
    // kvA rows: pack 8 d for each key with cvt_pk
#pragma unroll
    for (int p = 0; p < 4; ++p) {
      u32x4 w;
      w[0] = cvtpk(ra[p][0][0], ra[p][0][1]);
      w[1] = cvtpk(ra[p][0][2], ra[p][0][3]);
      w[2] = cvtpk(ra[p][1][0], ra[p][1][1]);
      w[3] = cvtpk(ra[p][1][2], ra[p][1][3]);
      const int key = kgrp * 4 + p;
      *(u32x4*)(kvAb + key * 256 + ((dg * 16) ^ ((key & 7) << 4))) = w;
    }
    // kvT columns: cvt_pk pairs ACROSS keys -> no element extraction needed
#pragma unroll
    for (int h = 0; h < 2; ++h)
#pragma unroll
      for (int ii = 0; ii < 4; ++ii) {
        const int d = dg * 8 + h * 4 + ii;
        u32x2 cw;
        cw[0] = cvtpk(ra[0][h][ii], ra[1][h][ii]);
        cw[1] = cvtpk(ra[2][h][ii], ra[3][h][ii]);
        *(u32x2*)(kvTb + d * 128 + ((kgrp * 8) ^ swzT(d))) = cw;
      }
  };

  float m_run = -1e30f;
  float l_run = 0.f;
  f32x4 o[8];
#pragma unroll
  for (int dc = 0; dc < 8; ++dc) o[dc] = (f32x4){0.f, 0.f, 0.f, 0.f};

  // ---- prologue: tile0 -> buf0, prefetch tile1 ----
  LOADRA(0);
  WRITELDS(0);
  LOADRA(KVB);
  asm volatile("s_waitcnt lgkmcnt(0)" ::: "memory");
  __builtin_amdgcn_s_barrier();
  int cur = 0;

  for (int kv0 = 0; kv0 < NSEQ; kv0 += KVB) {
    char* kvA = lds + cur * KVSTRIDE;
    char* kvT = kvA + 16384;

    // ---- swapped QK^T: D[key][q], q = lane&15, key = kb*16 + g*4 + r ----
    f32x4 sf[4];
#pragma unroll
    for (int kb = 0; kb < 4; ++kb) {
      sf[kb] = (f32x4){0.f, 0.f, 0.f, 0.f};
      const int key = kb * 16 + q15;  // A-frag row
#pragma unroll
      for (int c = 0; c < 4; ++c) {
        bf16x8 a = *(const bf16x8*)(kvA + key * 256 +
                                    ((c * 64 + g * 16) ^ ((key & 7) << 4)));
        sf[kb] = __builtin_amdgcn_mfma_f32_16x16x32_bf16(
            a, *(const bf16x8*)&qf[c], sf[kb], 0, 0, 0);
      }
    }

    // ---- online softmax (exp2 domain) with defer-max (T13) ----
    float mloc = -1e30f;
#pragma unroll
    for (int kb = 0; kb < 4; ++kb)
#pragma unroll
      for (int r = 0; r < 4; ++r) mloc = fmaxf(mloc, sf[kb][r]);
    mloc = fmaxf(mloc, __shfl_xor(mloc, 16));
    mloc = fmaxf(mloc, __shfl_xor(mloc, 32));
    if (!__all(mloc <= m_run + DEFER_THR)) {
      const float mnew = fmaxf(m_run, mloc);
      const float corr = fexp2(m_run - mnew);
#pragma unroll
      for (int r = 0; r < 4; ++r) {
        const float fr = __shfl(corr, g * 4 + r);
#pragma unroll
        for (int dc = 0; dc < 8; ++dc) o[dc][r] *= fr;
      }
      l_run *= corr;
      m_run = mnew;
    }
    float tsum = 0.f;
    float pf[4][4];
#pragma unroll
    for (int kb = 0; kb < 4; ++kb)
#pragma unroll
      for (int r = 0; r < 4; ++r) {
        const float pv = fexp2(sf[kb][r] - m_run);  // bounded by 2^DEFER_THR
        tsum += pv;
        pf[kb][r] = pv;
      }
    tsum += __shfl_xor(tsum, 16);
    tsum += __shfl_xor(tsum, 32);
    l_run += tsum;

    // ---- stage tile t+1 into the other buffer; issue prefetch of t+2 ----
    if (kv0 + KVB < NSEQ) {
      WRITELDS(cur ^ 1);
      LOADRA(kv0 + 2 * KVB);
    }

    // ---- P -> per-wave LDS (S^T D-layout -> PV A-layout) ----
#pragma unroll
    for (int kb = 0; kb < 4; ++kb) {
      u32x2 pw;
      pw[0] = cvtpk(pf[kb][0], pf[kb][1]);
      pw[1] = cvtpk(pf[kb][2], pf[kb][3]);
      *(u32x2*)(plds + wid * 2048 + q15 * 128 +
                ((kb * 32 + g * 8) ^ ((q15 & 7) << 4))) = pw;
    }

    // ---- PV: O[q][d] += P(16x64) . V(64x128) ----
#pragma unroll
    for (int kc = 0; kc < 2; ++kc) {
      bf16x8 pa = *(const bf16x8*)(plds + wid * 2048 + q15 * 128 +
                                   ((kc * 64 + g * 16) ^ ((q15 & 7) << 4)));
#pragma unroll
      for (int dc = 0; dc < 8; ++dc) {
        const int d = dc * 16 + q15;  // B-frag col
        bf16x8 vb = *(const bf16x8*)(kvT + d * 128 +
                                     ((kc * 64 + g * 16) ^ swzT(d)));
        o[dc] = __builtin_amdgcn_mfma_f32_16x16x32_bf16(pa, vb, o[dc], 0, 0, 0);
      }
    }

    // ---- single barrier per tile (raw: no vmcnt drain, prefetch stays live) ----
    asm volatile("s_waitcnt lgkmcnt(0)" ::: "memory");
    __builtin_amdgcn_s_barrier();
    cur ^= 1;
  }

  // ---- epilogue: normalize by l and store fp32 ----
#pragma unroll
  for (int r = 0; r < 4; ++r) {
    const float linv = 1.0f / __shfl(l_run, g * 4 + r);
    const int q = qbase + g * 4 + r;
    float* op = out + (size_t)bb * NSEQ * DH + (size_t)q * DH + q15;
#pragma unroll
    for (int dc = 0; dc < 8; ++dc) op[dc * 16] = o[dc][r] * linv;
  }
}

extern "C" void kernel_launch(void* const* d_in, const int* in_sizes, int n_in,
                              void* d_out, int out_size, void* d_ws, size_t ws_size,
                              hipStream_t stream) {
  const float* x1 = (const float*)d_in[0];
  const float* x2 = (const float*)d_in[1];
  float* out = (float*)d_out;
  dim3 grid(NSEQ / QBLK, 16);
  attn_fwd<<<grid, dim3(256), 0, stream>>>(x1, x2, out);
}

// Round 6
// 130.681 us; speedup vs baseline: 1.3420x; 1.0288x over previous
//
#include <hip/hip_runtime.h>
#include <hip/hip_bf16.h>

typedef __attribute__((ext_vector_type(8))) short bf16x8;
typedef __attribute__((ext_vector_type(4))) float f32x4;
typedef __attribute__((ext_vector_type(4))) unsigned u32x4;
typedef __attribute__((ext_vector_type(2))) unsigned u32x2;

#define NSEQ 2048
#define DH 128
#define QBLK 128
#define KVB 64
#define QSCALE 0.12751744716167933f /* (1/sqrt(128)) * log2(e) */
#define DEFER_THR 8.0f
#define KVSTRIDE 32768  /* kvA 16KB + kvT 16KB per buffer */

__device__ __forceinline__ unsigned cvtpk(float lo, float hi) {
  unsigned r;
  asm("v_cvt_pk_bf16_f32 %0, %1, %2" : "=v"(r) : "v"(lo), "v"(hi));
  return r;
}
__device__ __forceinline__ float fexp2(float x) { return __builtin_amdgcn_exp2f(x); }

// LDS swizzle for the transposed V tile rows (d = row, 128B rows)
__device__ __forceinline__ int swzT(int d) {
  return ((d & 7) ^ ((d >> 3) & 7)) << 4;
}

__global__ __launch_bounds__(256, 1) void attn_fwd(
    const float* __restrict__ x1, const float* __restrict__ x2,
    float* __restrict__ out) {
  // Double-buffered KV at 0 / 32KB; plds (4 waves x 2 subtiles x 2KB) at 64KB.
  __shared__ char lds[81920];
  char* plds = lds + 65536;

  const int tid = threadIdx.x;
  const int lane = tid & 63;
  const int wid = tid >> 6;
  const int g = lane >> 4;    // 0..3
  const int q15 = lane & 15;  // mfma row/col index

  const int bb = blockIdx.y;
  const int qbase = blockIdx.x * QBLK + wid * 32;  // wave owns 32 q-rows

  const float* x1b = x1 + (size_t)bb * NSEQ * DH;
  const float* x2b = x2 + (size_t)bb * NSEQ * DH;

  // Q fragments for 2 q-subtiles (B-layout for swapped QK^T), pre-scaled
  u32x4 qf[2][4];
#pragma unroll
  for (int s = 0; s < 2; ++s) {
    const float* qp = x1b + (size_t)(qbase + s * 16 + q15) * DH + g * 8;
#pragma unroll
    for (int c = 0; c < 4; ++c) {
      f32x4 v0 = *(const f32x4*)(qp + c * 32);
      f32x4 v1 = *(const f32x4*)(qp + c * 32 + 4);
      u32x4 w;
      w[0] = cvtpk(v0[0] * QSCALE, v0[1] * QSCALE);
      w[1] = cvtpk(v0[2] * QSCALE, v0[3] * QSCALE);
      w[2] = cvtpk(v1[0] * QSCALE, v1[1] * QSCALE);
      w[3] = cvtpk(v1[2] * QSCALE, v1[3] * QSCALE);
      qf[s][c] = w;
    }
  }

  // ---- staging identity: thread owns keys kgrp*4..+3, d = dg*8..+7 ----
  const int kgrp = tid >> 4;  // 0..15
  const int dg = tid & 15;    // 0..15
  f32x4 ra[4][2];             // prefetch regs

  auto LOADRA = [&](int kv0) {
    if (kv0 < NSEQ) {
#pragma unroll
      for (int p = 0; p < 4; ++p) {
        const float* s = x2b + (size_t)(kv0 + kgrp * 4 + p) * DH + dg * 8;
        ra[p][0] = *(const f32x4*)s;
        ra[p][1] = *(const f32x4*)(s + 4);
      }
    }
  };

  auto WRITELDS = [&](int b) {
    char* kvAb = lds + b * KVSTRIDE;
    char* kvTb = kvAb + 16384;
#pragma unroll
    for (int p = 0; p < 4; ++p) {
      u32x4 w;
      w[0] = cvtpk(ra[p][0][0], ra[p][0][1]);
      w[1] = cvtpk(ra[p][0][2], ra[p][0][3]);
      w[2] = cvtpk(ra[p][1][0], ra[p][1][1]);
      w[3] = cvtpk(ra[p][1][2], ra[p][1][3]);
      const int key = kgrp * 4 + p;
      *(u32x4*)(kvAb + key * 256 + ((dg * 16) ^ ((key & 7) << 4))) = w;
    }
    // kvT columns: cvt_pk pairs ACROSS keys
#pragma unroll
    for (int h = 0; h < 2; ++h)
#pragma unroll
      for (int ii = 0; ii < 4; ++ii) {
        const int d = dg * 8 + h * 4 + ii;
        u32x2 cw;
        cw[0] = cvtpk(ra[0][h][ii], ra[1][h][ii]);
        cw[1] = cvtpk(ra[2][h][ii], ra[3][h][ii]);
        *(u32x2*)(kvTb + d * 128 + ((kgrp * 8) ^ swzT(d))) = cw;
      }
  };

  float m_run[2] = {-1e30f, -1e30f};
  float l_run[2] = {0.f, 0.f};
  f32x4 o[2][8];  // O^T fragments: element [d=dc*16+g*4+r][q=q15]
#pragma unroll
  for (int s = 0; s < 2; ++s)
#pragma unroll
    for (int dc = 0; dc < 8; ++dc) o[s][dc] = (f32x4){0.f, 0.f, 0.f, 0.f};

  // ---- prologue ----
  LOADRA(0);
  WRITELDS(0);
  LOADRA(KVB);
  asm volatile("s_waitcnt lgkmcnt(0)" ::: "memory");
  __builtin_amdgcn_s_barrier();
  int cur = 0;

  for (int kv0 = 0; kv0 < NSEQ; kv0 += KVB) {
    char* kvA = lds + cur * KVSTRIDE;
    char* kvT = kvA + 16384;

    // ---- swapped QK^T: K-frag read once, feeds both q-subtiles ----
    f32x4 sf[2][4];
#pragma unroll
    for (int kb = 0; kb < 4; ++kb) {
      sf[0][kb] = (f32x4){0.f, 0.f, 0.f, 0.f};
      sf[1][kb] = (f32x4){0.f, 0.f, 0.f, 0.f};
      const int key = kb * 16 + q15;
#pragma unroll
      for (int c = 0; c < 4; ++c) {
        bf16x8 a = *(const bf16x8*)(kvA + key * 256 +
                                    ((c * 64 + g * 16) ^ ((key & 7) << 4)));
        sf[0][kb] = __builtin_amdgcn_mfma_f32_16x16x32_bf16(
            a, *(const bf16x8*)&qf[0][c], sf[0][kb], 0, 0, 0);
        sf[1][kb] = __builtin_amdgcn_mfma_f32_16x16x32_bf16(
            a, *(const bf16x8*)&qf[1][c], sf[1][kb], 0, 0, 0);
      }
    }

    // ---- online softmax (exp2 domain), defer-max, both subtiles ----
    float mloc[2];
#pragma unroll
    for (int s = 0; s < 2; ++s) {
      float m = -1e30f;
#pragma unroll
      for (int kb = 0; kb < 4; ++kb)
#pragma unroll
        for (int r = 0; r < 4; ++r) m = fmaxf(m, sf[s][kb][r]);
      m = fmaxf(m, __shfl_xor(m, 16));
      m = fmaxf(m, __shfl_xor(m, 32));
      mloc[s] = m;
    }
    const bool ok = (mloc[0] <= m_run[0] + DEFER_THR) &&
                    (mloc[1] <= m_run[1] + DEFER_THR);
    if (!__all(ok)) {
#pragma unroll
      for (int s = 0; s < 2; ++s) {
        const float mnew = fmaxf(m_run[s], mloc[s]);
        const float corr = fexp2(m_run[s] - mnew);  // lane-local: o col = q15
#pragma unroll
        for (int dc = 0; dc < 8; ++dc) o[s][dc] *= corr;
        l_run[s] *= corr;
        m_run[s] = mnew;
      }
    }
#pragma unroll
    for (int s = 0; s < 2; ++s) {
      float tsum = 0.f;
      float pf[4][4];
#pragma unroll
      for (int kb = 0; kb < 4; ++kb)
#pragma unroll
        for (int r = 0; r < 4; ++r) {
          const float pv = fexp2(sf[s][kb][r] - m_run[s]);
          tsum += pv;
          pf[kb][r] = pv;
        }
      tsum += __shfl_xor(tsum, 16);
      tsum += __shfl_xor(tsum, 32);
      l_run[s] += tsum;
      // P -> per-wave-per-subtile LDS (S^T D-layout -> PV operand layout)
#pragma unroll
      for (int kb = 0; kb < 4; ++kb) {
        u32x2 pw;
        pw[0] = cvtpk(pf[kb][0], pf[kb][1]);
        pw[1] = cvtpk(pf[kb][2], pf[kb][3]);
        *(u32x2*)(plds + wid * 4096 + s * 2048 + q15 * 128 +
                  ((kb * 32 + g * 8) ^ ((q15 & 7) << 4))) = pw;
      }
    }

    // ---- stage tile t+1 into other buffer; prefetch t+2 ----
    if (kv0 + KVB < NSEQ) {
      WRITELDS(cur ^ 1);
      LOADRA(kv0 + 2 * KVB);
    }

    // ---- PV as O^T: V-frag read once, feeds both subtiles ----
#pragma unroll
    for (int kc = 0; kc < 2; ++kc) {
      bf16x8 pa0 = *(const bf16x8*)(plds + wid * 4096 + q15 * 128 +
                                    ((kc * 64 + g * 16) ^ ((q15 & 7) << 4)));
      bf16x8 pa1 = *(const bf16x8*)(plds + wid * 4096 + 2048 + q15 * 128 +
                                    ((kc * 64 + g * 16) ^ ((q15 & 7) << 4)));
#pragma unroll
      for (int dc = 0; dc < 8; ++dc) {
        const int d = dc * 16 + q15;  // A-frag row = d_local
        bf16x8 vb = *(const bf16x8*)(kvT + d * 128 +
                                     ((kc * 64 + g * 16) ^ swzT(d)));
        o[0][dc] = __builtin_amdgcn_mfma_f32_16x16x32_bf16(vb, pa0, o[0][dc], 0, 0, 0);
        o[1][dc] = __builtin_amdgcn_mfma_f32_16x16x32_bf16(vb, pa1, o[1][dc], 0, 0, 0);
      }
    }

    // ---- single raw barrier per tile (prefetch stays in flight) ----
    asm volatile("s_waitcnt lgkmcnt(0)" ::: "memory");
    __builtin_amdgcn_s_barrier();
    cur ^= 1;
  }

  // ---- epilogue: normalize (lane-local l) and store contiguous f32x4 ----
#pragma unroll
  for (int s = 0; s < 2; ++s) {
    const float linv = 1.0f / l_run[s];
    float* op = out + (size_t)bb * NSEQ * DH + (size_t)(qbase + s * 16 + q15) * DH;
#pragma unroll
    for (int dc = 0; dc < 8; ++dc) {
      f32x4 v = o[s][dc] * linv;  // elements d = dc*16 + g*4 + r, r contiguous
      *(f32x4*)(op + dc * 16 + g * 4) = v;
    }
  }
}

extern "C" void kernel_launch(void* const* d_in, const int* in_sizes, int n_in,
                              void* d_out, int out_size, void* d_ws, size_t ws_size,
                              hipStream_t stream) {
  const float* x1 = (const float*)d_in[0];
  const float* x2 = (const float*)d_in[1];
  float* out = (float*)d_out;
  dim3 grid(NSEQ / QBLK, 16);
  attn_fwd<<<grid, dim3(256), 0, stream>>>(x1, x2, out);
}

// Round 9
// 130.343 us; speedup vs baseline: 1.3455x; 1.0026x over previous
//
#include <hip/hip_runtime.h>
#include <hip/hip_bf16.h>

typedef __attribute__((ext_vector_type(8))) short bf16x8;
typedef __attribute__((ext_vector_type(4))) float f32x4;
typedef __attribute__((ext_vector_type(4))) unsigned u32x4;
typedef __attribute__((ext_vector_type(2))) unsigned u32x2;

#define NSEQ 2048
#define DH 128
#define QBLK 128
#define KVB 64
#define QSCALE 0.12751744716167933f /* (1/sqrt(128)) * log2(e) */
#define DEFER_THR 8.0f
#define KVBUF 32768  /* kvA 16KB + kvT 16KB per buffer */

__device__ __forceinline__ unsigned cvtpk(float lo, float hi) {
  unsigned r;
  asm("v_cvt_pk_bf16_f32 %0, %1, %2" : "=v"(r) : "v"(lo), "v"(hi));
  return r;
}
__device__ __forceinline__ float fexp2(float x) { return __builtin_amdgcn_exp2f(x); }

__device__ __forceinline__ void wg_barrier() {
  asm volatile("s_waitcnt lgkmcnt(0)" ::: "memory");
  __builtin_amdgcn_s_barrier();
  asm volatile("" ::: "memory");
}

// LDS swizzle for the transposed V tile rows (d = row, 128B rows)
__device__ __forceinline__ int swzT(int d) {
  return ((d & 7) ^ ((d >> 3) & 7)) << 4;
}

__global__ __launch_bounds__(256, 1) void attn_fwd(
    const float* __restrict__ x1, const float* __restrict__ x2,
    float* __restrict__ out) {
  // Double-buffered KV only (P never touches LDS). 64 KB total.
  __shared__ char lds[65536];

  const int tid = threadIdx.x;
  const int lane = tid & 63;
  const int wid = tid >> 6;
  const int g = lane >> 4;    // 0..3
  const int q15 = lane & 15;  // mfma row/col index

  const int bb = blockIdx.y;
  const int qbase = blockIdx.x * QBLK + wid * 32;  // wave owns 32 q-rows

  const float* x1b = x1 + (size_t)bb * NSEQ * DH;
  const float* x2b = x2 + (size_t)bb * NSEQ * DH;

  // Q fragments for 2 q-subtiles (B-layout for swapped QK^T), pre-scaled
  u32x4 qf[2][4];
#pragma unroll
  for (int s = 0; s < 2; ++s) {
    const float* qp = x1b + (size_t)(qbase + s * 16 + q15) * DH + g * 8;
#pragma unroll
    for (int c = 0; c < 4; ++c) {
      f32x4 v0 = *(const f32x4*)(qp + c * 32);
      f32x4 v1 = *(const f32x4*)(qp + c * 32 + 4);
      u32x4 w;
      w[0] = cvtpk(v0[0] * QSCALE, v0[1] * QSCALE);
      w[1] = cvtpk(v0[2] * QSCALE, v0[3] * QSCALE);
      w[2] = cvtpk(v1[0] * QSCALE, v1[1] * QSCALE);
      w[3] = cvtpk(v1[2] * QSCALE, v1[3] * QSCALE);
      qf[s][c] = w;
    }
  }

  // ---- staging identity: thread owns keys kgrp*4..+3, d = dg*8..+7 ----
  const int kgrp = tid >> 4;  // 0..15
  const int dg = tid & 15;    // 0..15
  f32x4 ra[4][2];             // prefetch regs

  auto LOADRA = [&](int kv0) {
    if (kv0 < NSEQ) {
#pragma unroll
      for (int p = 0; p < 4; ++p) {
        const float* s = x2b + (size_t)(kv0 + kgrp * 4 + p) * DH + dg * 8;
        ra[p][0] = *(const f32x4*)s;
        ra[p][1] = *(const f32x4*)(s + 4);
      }
    }
  };

  auto WRITELDS = [&](int b) {
    char* kvAb = lds + b * KVBUF;
    char* kvTb = kvAb + 16384;
    // kvA rows: PERMUTED row index rho. key bits [kc|g|b|r] -> row bits
    // [kc|b|g|r]. Softmax is permutation-invariant over keys, and this makes
    // each lane's QK outputs exactly the keys its PV B-operand needs
    // (in ascending order) -> P stays in registers, no LDS round-trip.
#pragma unroll
    for (int p = 0; p < 4; ++p) {
      u32x4 w;
      w[0] = cvtpk(ra[p][0][0], ra[p][0][1]);
      w[1] = cvtpk(ra[p][0][2], ra[p][0][3]);
      w[2] = cvtpk(ra[p][1][0], ra[p][1][1]);
      w[3] = cvtpk(ra[p][1][2], ra[p][1][3]);
      const int key = kgrp * 4 + p;
      const int rho = (key & 0x23) | ((key & 4) << 2) | ((key & 0x18) >> 1);
      *(u32x4*)(kvAb + rho * 256 + ((dg * 16) ^ ((rho & 7) << 4))) = w;
    }
    // kvT columns: NATURAL key order (must match PV's B-operand k-slots)
#pragma unroll
    for (int h = 0; h < 2; ++h)
#pragma unroll
      for (int ii = 0; ii < 4; ++ii) {
        const int d = dg * 8 + h * 4 + ii;
        u32x2 cw;
        cw[0] = cvtpk(ra[0][h][ii], ra[1][h][ii]);
        cw[1] = cvtpk(ra[2][h][ii], ra[3][h][ii]);
        *(u32x2*)(kvTb + d * 128 + ((kgrp * 8) ^ swzT(d))) = cw;
      }
  };

  float m_run[2] = {-1e30f, -1e30f};
  float l_run[2] = {0.f, 0.f};
  f32x4 o[2][8];  // O^T fragments: [d=dc*16+g*4+r][q=q15]
#pragma unroll
  for (int s = 0; s < 2; ++s)
#pragma unroll
    for (int dc = 0; dc < 8; ++dc) o[s][dc] = (f32x4){0.f, 0.f, 0.f, 0.f};

  // ---- prologue: tile0 -> buf0, prefetch tile1 ----
  LOADRA(0);
  WRITELDS(0);
  LOADRA(KVB);
  wg_barrier();
  int cur = 0;

  for (int kv0 = 0; kv0 < NSEQ; kv0 += KVB) {
    char* kvA = lds + cur * KVBUF;
    char* kvT = kvA + 16384;

    // ---- swapped QK^T: sf[s][kb][r] = S[q][key = perm(16kb+4g+r)] ----
    f32x4 sf[2][4];
#pragma unroll
    for (int kb = 0; kb < 4; ++kb) {
      sf[0][kb] = (f32x4){0.f, 0.f, 0.f, 0.f};
      sf[1][kb] = (f32x4){0.f, 0.f, 0.f, 0.f};
      const int row = kb * 16 + q15;  // A-frag row (permuted key space)
#pragma unroll
      for (int c = 0; c < 4; ++c) {
        bf16x8 a = *(const bf16x8*)(kvA + row * 256 +
                                    ((c * 64 + g * 16) ^ ((row & 7) << 4)));
        sf[0][kb] = __builtin_amdgcn_mfma_f32_16x16x32_bf16(
            a, *(const bf16x8*)&qf[0][c], sf[0][kb], 0, 0, 0);
        sf[1][kb] = __builtin_amdgcn_mfma_f32_16x16x32_bf16(
            a, *(const bf16x8*)&qf[1][c], sf[1][kb], 0, 0, 0);
      }
    }

    // ---- online softmax (exp2 domain, defer-max); P packed IN REGISTERS ----
    u32x4 pa[2][2];  // [subtile][kc]: B-operand fragments for PV
    float mloc[2];
#pragma unroll
    for (int s = 0; s < 2; ++s) {
      float m = -1e30f;
#pragma unroll
      for (int kb = 0; kb < 4; ++kb)
#pragma unroll
        for (int r = 0; r < 4; ++r) m = fmaxf(m, sf[s][kb][r]);
      m = fmaxf(m, __shfl_xor(m, 16));
      m = fmaxf(m, __shfl_xor(m, 32));
      mloc[s] = m;
    }
    const bool ok = (mloc[0] <= m_run[0] + DEFER_THR) &&
                    (mloc[1] <= m_run[1] + DEFER_THR);
    if (!__all(ok)) {
#pragma unroll
      for (int s = 0; s < 2; ++s) {
        const float mnew = fmaxf(m_run[s], mloc[s]);
        const float corr = fexp2(m_run[s] - mnew);  // lane-local: o col = q15
#pragma unroll
        for (int dc = 0; dc < 8; ++dc) o[s][dc] *= corr;
        l_run[s] *= corr;
        m_run[s] = mnew;
      }
    }
#pragma unroll
    for (int s = 0; s < 2; ++s) {
      float tsum = 0.f;
      float pf[4][4];
#pragma unroll
      for (int kb = 0; kb < 4; ++kb)
#pragma unroll
        for (int r = 0; r < 4; ++r) {
          const float pv = fexp2(sf[s][kb][r] - m_run[s]);
          tsum += pv;
          pf[kb][r] = pv;
        }
      tsum += __shfl_xor(tsum, 16);
      tsum += __shfl_xor(tsum, 32);
      l_run[s] += tsum;
      // pack: pa[s][kc] slots = keys kc*32 + g*8 + {0..7} (by construction)
#pragma unroll
      for (int kc = 0; kc < 2; ++kc) {
        u32x4 w;
        w[0] = cvtpk(pf[2 * kc][0], pf[2 * kc][1]);
        w[1] = cvtpk(pf[2 * kc][2], pf[2 * kc][3]);
        w[2] = cvtpk(pf[2 * kc + 1][0], pf[2 * kc + 1][1]);
        w[3] = cvtpk(pf[2 * kc + 1][2], pf[2 * kc + 1][3]);
        pa[s][kc] = w;
      }
    }

    // ---- stage tile t+1 into other buffer; prefetch t+2 ----
    if (kv0 + KVB < NSEQ) {
      WRITELDS(cur ^ 1);
      LOADRA(kv0 + 2 * KVB);
    }

    // ---- PV as O^T: vb read once, feeds both subtiles; pa from registers ----
#pragma unroll
    for (int kc = 0; kc < 2; ++kc) {
#pragma unroll
      for (int dc = 0; dc < 8; ++dc) {
        const int d = dc * 16 + q15;
        bf16x8 vb = *(const bf16x8*)(kvT + d * 128 +
                                     ((kc * 64 + g * 16) ^ swzT(d)));
        o[0][dc] = __builtin_amdgcn_mfma_f32_16x16x32_bf16(
            vb, *(const bf16x8*)&pa[0][kc], o[0][dc], 0, 0, 0);
        o[1][dc] = __builtin_amdgcn_mfma_f32_16x16x32_bf16(
            vb, *(const bf16x8*)&pa[1][kc], o[1][dc], 0, 0, 0);
      }
    }

    wg_barrier();
    cur ^= 1;
  }

  // ---- epilogue: normalize (lane-local l) and store contiguous f32x4 ----
#pragma unroll
  for (int s = 0; s < 2; ++s) {
    const float linv = 1.0f / l_run[s];
    float* op = out + (size_t)bb * NSEQ * DH + (size_t)(qbase + s * 16 + q15) * DH;
#pragma unroll
    for (int dc = 0; dc < 8; ++dc) {
      f32x4 v = o[s][dc] * linv;
      *(f32x4*)(op + dc * 16 + g * 4) = v;
    }
  }
}

extern "C" void kernel_launch(void* const* d_in, const int* in_sizes, int n_in,
                              void* d_out, int out_size, void* d_ws, size_t ws_size,
                              hipStream_t stream) {
  const float* x1 = (const float*)d_in[0];
  const float* x2 = (const float*)d_in[1];
  float* out = (float*)d_out;
  dim3 grid(NSEQ / QBLK, 16);
  attn_fwd<<<grid, dim3(256), 0, stream>>>(x1, x2, out);
}

// Round 11
// 127.253 us; speedup vs baseline: 1.3782x; 1.0243x over previous
//
#include <hip/hip_runtime.h>
#include <hip/hip_bf16.h>

typedef __attribute__((ext_vector_type(8))) short bf16x8;
typedef __attribute__((ext_vector_type(4))) float f32x4;
typedef __attribute__((ext_vector_type(4))) unsigned u32x4;

#define NSEQ 2048
#define DH 128
#define QBLK 128
#define KVB 64
#define QSCALE 0.12751744716167933f /* (1/sqrt(128)) * log2(e) */
#define DEFER_THR 8.0f
#define KVBUF 32768  /* kvA 16KB + kvT 16KB per buffer */

__device__ __forceinline__ unsigned cvtpk(float lo, float hi) {
  unsigned r;
  asm("v_cvt_pk_bf16_f32 %0, %1, %2" : "=v"(r) : "v"(lo), "v"(hi));
  return r;
}
__device__ __forceinline__ float fexp2(float x) { return __builtin_amdgcn_exp2f(x); }

__device__ __forceinline__ void wg_barrier() {
  asm volatile("s_waitcnt lgkmcnt(0)" ::: "memory");
  __builtin_amdgcn_s_barrier();
  asm volatile("" ::: "memory");
}

// LDS swizzle for the transposed V tile rows (d = row, 128B rows)
__device__ __forceinline__ int swzT(int d) {
  return ((d & 7) ^ ((d >> 3) & 7)) << 4;
}

__global__ __launch_bounds__(512, 2) void attn_fwd(
    const float* __restrict__ x1, const float* __restrict__ x2,
    float* __restrict__ out) {
  // Double-buffered KV shared by all 8 waves. 64 KB total (<=80KB rule:
  // every 128KB-LDS variant failed deterministically; see session journal).
  __shared__ char lds[65536];

  const int tid = threadIdx.x;
  const int lane = tid & 63;
  const int wid = tid >> 6;   // 0..7, wave owns 16 q-rows
  const int g = lane >> 4;    // 0..3
  const int q15 = lane & 15;  // mfma row/col index

  const int bb = blockIdx.y;
  const int qbase = blockIdx.x * QBLK + wid * 16;

  const float* x1b = x1 + (size_t)bb * NSEQ * DH;
  const float* x2b = x2 + (size_t)bb * NSEQ * DH;

  // Q fragment (B-layout for swapped QK^T), pre-scaled by QSCALE
  u32x4 qf[4];
  {
    const float* qp = x1b + (size_t)(qbase + q15) * DH + g * 8;
#pragma unroll
    for (int c = 0; c < 4; ++c) {
      f32x4 v0 = *(const f32x4*)(qp + c * 32);
      f32x4 v1 = *(const f32x4*)(qp + c * 32 + 4);
      u32x4 w;
      w[0] = cvtpk(v0[0] * QSCALE, v0[1] * QSCALE);
      w[1] = cvtpk(v0[2] * QSCALE, v0[3] * QSCALE);
      w[2] = cvtpk(v1[0] * QSCALE, v1[1] * QSCALE);
      w[3] = cvtpk(v1[2] * QSCALE, v1[3] * QSCALE);
      qf[c] = w;
    }
  }

  // ---- staging identity: 512 threads, thread owns keys kg*2..+1, d=dg*8..+7
  const int kg = tid >> 4;  // 0..31
  const int dg = tid & 15;  // 0..15
  f32x4 ra[2][2];           // prefetch regs

  auto LOADRA = [&](int kv0) {
    if (kv0 < NSEQ) {
#pragma unroll
      for (int p = 0; p < 2; ++p) {
        const float* s = x2b + (size_t)(kv0 + kg * 2 + p) * DH + dg * 8;
        ra[p][0] = *(const f32x4*)s;
        ra[p][1] = *(const f32x4*)(s + 4);
      }
    }
  };

  auto WRITELDS = [&](int b) {
    char* kvAb = lds + b * KVBUF;
    char* kvTb = kvAb + 16384;
    // kvA rows: PERMUTED row rho (key bits [kc|g|b|r] -> [kc|b|g|r]):
    // softmax is permutation-invariant over keys; each lane's QK outputs are
    // then exactly its PV B-operand keys -> P stays in registers.
#pragma unroll
    for (int p = 0; p < 2; ++p) {
      u32x4 w;
      w[0] = cvtpk(ra[p][0][0], ra[p][0][1]);
      w[1] = cvtpk(ra[p][0][2], ra[p][0][3]);
      w[2] = cvtpk(ra[p][1][0], ra[p][1][1]);
      w[3] = cvtpk(ra[p][1][2], ra[p][1][3]);
      const int key = kg * 2 + p;
      const int rho = (key & 0x23) | ((key & 4) << 2) | ((key & 0x18) >> 1);
      *(u32x4*)(kvAb + rho * 256 + ((dg * 16) ^ ((rho & 7) << 4))) = w;
    }
    // kvT columns: NATURAL key order; 2 keys -> one b32 per d
#pragma unroll
    for (int h = 0; h < 2; ++h)
#pragma unroll
      for (int ii = 0; ii < 4; ++ii) {
        const int d = dg * 8 + h * 4 + ii;
        const unsigned cw = cvtpk(ra[0][h][ii], ra[1][h][ii]);
        *(unsigned*)(kvTb + d * 128 + ((kg * 4) ^ swzT(d))) = cw;
      }
  };

  float m_run = -1e30f;
  float l_run = 0.f;
  f32x4 o[8];  // O^T fragments: [d=dc*16+g*4+r][q=q15]
#pragma unroll
  for (int dc = 0; dc < 8; ++dc) o[dc] = (f32x4){0.f, 0.f, 0.f, 0.f};

  // ---- prologue: tile0 -> buf0, prefetch tile1 ----
  LOADRA(0);
  WRITELDS(0);
  LOADRA(KVB);
  wg_barrier();
  int cur = 0;

  for (int kv0 = 0; kv0 < NSEQ; kv0 += KVB) {
    char* kvA = lds + cur * KVBUF;
    char* kvT = kvA + 16384;

    // ---- swapped QK^T: sf[kb][r] = S[q][key = perm(16kb+4g+r)] ----
    f32x4 sf[4];
#pragma unroll
    for (int kb = 0; kb < 4; ++kb) {
      sf[kb] = (f32x4){0.f, 0.f, 0.f, 0.f};
      const int row = kb * 16 + q15;  // A-frag row (permuted key space)
#pragma unroll
      for (int c = 0; c < 4; ++c) {
        bf16x8 a = *(const bf16x8*)(kvA + row * 256 +
                                    ((c * 64 + g * 16) ^ ((row & 7) << 4)));
        sf[kb] = __builtin_amdgcn_mfma_f32_16x16x32_bf16(
            a, *(const bf16x8*)&qf[c], sf[kb], 0, 0, 0);
      }
    }

    // ---- online softmax (exp2 domain, defer-max); P packed IN REGISTERS ----
    float mloc = -1e30f;
#pragma unroll
    for (int kb = 0; kb < 4; ++kb)
#pragma unroll
      for (int r = 0; r < 4; ++r) mloc = fmaxf(mloc, sf[kb][r]);
    mloc = fmaxf(mloc, __shfl_xor(mloc, 16));
    mloc = fmaxf(mloc, __shfl_xor(mloc, 32));
    if (!__all(mloc <= m_run + DEFER_THR)) {
      const float mnew = fmaxf(m_run, mloc);
      const float corr = fexp2(m_run - mnew);  // lane-local: o col = q15
#pragma unroll
      for (int dc = 0; dc < 8; ++dc) o[dc] *= corr;
      l_run *= corr;
      m_run = mnew;
    }
    float tsum = 0.f;
    float pf[4][4];
#pragma unroll
    for (int kb = 0; kb < 4; ++kb)
#pragma unroll
      for (int r = 0; r < 4; ++r) {
        const float pv = fexp2(sf[kb][r] - m_run);  // bounded by 2^DEFER_THR
        tsum += pv;
        pf[kb][r] = pv;
      }
    tsum += __shfl_xor(tsum, 16);
    tsum += __shfl_xor(tsum, 32);
    l_run += tsum;
    u32x4 pa[2];  // PV B-operand: keys kc*32 + g*8 + {0..7} (by construction)
#pragma unroll
    for (int kc = 0; kc < 2; ++kc) {
      u32x4 w;
      w[0] = cvtpk(pf[2 * kc][0], pf[2 * kc][1]);
      w[1] = cvtpk(pf[2 * kc][2], pf[2 * kc][3]);
      w[2] = cvtpk(pf[2 * kc + 1][0], pf[2 * kc + 1][1]);
      w[3] = cvtpk(pf[2 * kc + 1][2], pf[2 * kc + 1][3]);
      pa[kc] = w;
    }

    // ---- stage tile t+1 into other buffer; prefetch t+2 ----
    if (kv0 + KVB < NSEQ) {
      WRITELDS(cur ^ 1);
      LOADRA(kv0 + 2 * KVB);
    }

    // ---- PV as O^T: pa from registers, vb from LDS ----
#pragma unroll
    for (int kc = 0; kc < 2; ++kc) {
#pragma unroll
      for (int dc = 0; dc < 8; ++dc) {
        const int d = dc * 16 + q15;
        bf16x8 vb = *(const bf16x8*)(kvT + d * 128 +
                                     ((kc * 64 + g * 16) ^ swzT(d)));
        o[dc] = __builtin_amdgcn_mfma_f32_16x16x32_bf16(
            vb, *(const bf16x8*)&pa[kc], o[dc], 0, 0, 0);
      }
    }

    wg_barrier();
    cur ^= 1;
  }

  // ---- epilogue: normalize (lane-local l) and store contiguous f32x4 ----
  {
    const float linv = 1.0f / l_run;
    float* op = out + (size_t)bb * NSEQ * DH + (size_t)(qbase + q15) * DH;
#pragma unroll
    for (int dc = 0; dc < 8; ++dc) {
      f32x4 v = o[dc] * linv;  // elements d = dc*16 + g*4 + r
      *(f32x4*)(op + dc * 16 + g * 4) = v;
    }
  }
}

extern "C" void kernel_launch(void* const* d_in, const int* in_sizes, int n_in,
                              void* d_out, int out_size, void* d_ws, size_t ws_size,
                              hipStream_t stream) {
  const float* x1 = (const float*)d_in[0];
  const float* x2 = (const float*)d_in[1];
  float* out = (float*)d_out;
  dim3 grid(NSEQ / QBLK, 16);
  attn_fwd<<<grid, dim3(512), 0, stream>>>(x1, x2, out);
}